// Round 15
// baseline (2092.155 us; speedup 1.0000x reference)
//
#include <hip/hip_runtime.h>
#include <math.h>

#define BB 16
#define SS 256
#define WW 128
#define HH 768
#define LL 12
#define NHH 12
#define DHH 64
#define FFD 3072
#define CC 425
#define NTOK (BB*SS)
#define QKVN (3*HH)   // 2304

typedef __attribute__((ext_vector_type(8))) short bf16x8;
typedef __attribute__((ext_vector_type(4))) float f32x4;

__device__ __forceinline__ float bf2f(unsigned short u) {
    union { unsigned int i; float f; } z; z.i = ((unsigned int)u) << 16; return z.f;
}
__device__ __forceinline__ unsigned short f2bf(float f) {
    union { float f; unsigned int i; } z; z.f = f;
    unsigned int i = z.i;
    unsigned int r = (i + 0x7fffu + ((i >> 16) & 1u)) >> 16;
    return (unsigned short)r;
}

__device__ __forceinline__ void gload16(const void* g, void* l) {
    __builtin_amdgcn_global_load_lds((const __attribute__((address_space(1))) void*)g,
                                     (__attribute__((address_space(3))) void*)l, 16, 0, 0);
}

// gelu via A&S 7.1.26 erf (|err|<=1.5e-7, invisible at bf16) + __expf
__device__ __forceinline__ float gelu_f(float v) {
    float ax = fabsf(v) * 0.70710678118654752f;
    float t = 1.0f / fmaf(0.3275911f, ax, 1.0f);
    float poly = t * fmaf(t, fmaf(t, fmaf(t, fmaf(t, 1.061405429f, -1.453152027f),
                                          1.421413741f), -0.284496736f), 0.254829592f);
    float er = 1.0f - poly * __expf(-ax * ax);
    er = (v < 0.f) ? -er : er;
    return 0.5f * v * (1.0f + er);
}

__device__ __forceinline__ int xcd_remap(int nwg, int orig) {
    int q = nwg >> 3, r = nwg & 7, xc = orig & 7, o8 = orig >> 3;
    return (xc < r ? xc * (q + 1) : r * (q + 1) + (xc - r) * q) + o8;
}

// ---------------------------------------------------------------------------
// 128x128 GEMM, 512 threads / 8 waves (wave tile 64x32), R7 2-phase dbuf.
// ACT_C: 0 none, 1 gelu, 2 relu.
// ---------------------------------------------------------------------------
template<int ACT_C>
__launch_bounds__(512)
__global__ void gemm128(const unsigned short* __restrict__ A,
                        const unsigned short* __restrict__ Bt,
                        const float* __restrict__ bias,
                        unsigned short* __restrict__ Cm,
                        int M, int N, int K, int ldC) {
    constexpr int BUFS = 128 * 32;   // shorts per buffer
    __shared__ __align__(16) unsigned short lA[2 * BUFS];
    __shared__ __align__(16) unsigned short lB[2 * BUFS];
    const int tid = threadIdx.x, w = tid >> 6, l = tid & 63;

    const int gx = gridDim.x;
    const int wg = xcd_remap(gx * gridDim.y, blockIdx.y * gx + blockIdx.x);
    const int m0 = (wg / gx) * 128, n0 = (wg % gx) * 128;

    const int wr = (w >> 2) * 64, wc = (w & 3) * 32;
    const int lr = l & 15, lk = (l >> 4) * 8;
    const int rsw = ((lr >> 1) & 3) << 4;
    const int lrow = l >> 2;
    const int gs = (l & 3) ^ ((lrow >> 1) & 3);

    f32x4 acc[4][2];
#pragma unroll
    for (int m = 0; m < 4; ++m)
#pragma unroll
        for (int n = 0; n < 2; ++n) acc[m][n] = (f32x4){0.f, 0.f, 0.f, 0.f};

    auto stage = [&](int k0, unsigned short* dA, unsigned short* dB) {
        gload16(A + (size_t)(m0 + w * 16 + lrow) * K + k0 + gs * 8, dA + w * 512);
        gload16(Bt + (size_t)(n0 + w * 16 + lrow) * K + k0 + gs * 8, dB + w * 512);
    };

    const int nt = K >> 5;
    stage(0, lA, lB);
    __syncthreads();

    for (int t = 0; t < nt; ++t) {
        unsigned short* cA = lA + (t & 1) * BUFS;
        unsigned short* cB = lB + (t & 1) * BUFS;
        if (t + 1 < nt)
            stage((t + 1) << 5, lA + ((t + 1) & 1) * BUFS, lB + ((t + 1) & 1) * BUFS);
        bf16x8 af[4], bfr[2];
#pragma unroll
        for (int m = 0; m < 4; ++m) {
            int row = wr + m * 16 + lr;
            af[m] = *(const bf16x8*)((const char*)cA + row * 64 + ((lk * 2) ^ rsw));
        }
#pragma unroll
        for (int n = 0; n < 2; ++n) {
            int row = wc + n * 16 + lr;
            bfr[n] = *(const bf16x8*)((const char*)cB + row * 64 + ((lk * 2) ^ rsw));
        }
#pragma unroll
        for (int m = 0; m < 4; ++m)
#pragma unroll
            for (int n = 0; n < 2; ++n)
                acc[m][n] = __builtin_amdgcn_mfma_f32_16x16x32_bf16(af[m], bfr[n], acc[m][n], 0, 0, 0);
        __syncthreads();
    }

    const int orow = (l >> 4) * 4, ocol = l & 15;
#pragma unroll
    for (int m = 0; m < 4; ++m)
#pragma unroll
        for (int n = 0; n < 2; ++n) {
            int c = n0 + wc + n * 16 + ocol;
            if (c >= N) continue;
            float bb = bias[c];
#pragma unroll
            for (int j = 0; j < 4; ++j) {
                int rr = m0 + wr + m * 16 + orow + j;
                float vv = acc[m][n][j] + bb;
                if (ACT_C == 1) vv = gelu_f(vv);
                if (ACT_C == 2) vv = fmaxf(vv, 0.f);
                Cm[(size_t)rr * ldC + c] = f2bf(vv);
            }
        }
}

// ---------------------------------------------------------------------------
// 64x128 GEMM, 512 threads / 8 waves (2x4 wave grid, wave tile 32x32), BK=32
// 2-phase dbuf, LDS 24KB -> 4 blocks/CU x 8 waves = 32 waves/CU (R14 lever
// applied to the QKV shape). Staging: wave w stages B-stripe w (rows w*16);
// waves 0-3 also stage A-stripe w. Proven slot swizzle; linear LDS dest.
// ---------------------------------------------------------------------------
template<int ACT_C>
__launch_bounds__(512)
__global__ void gemm64x128(const unsigned short* __restrict__ A,
                           const unsigned short* __restrict__ Bt,
                           const float* __restrict__ bias,
                           unsigned short* __restrict__ Cm,
                           int M, int N, int K, int ldC) {
    constexpr int ASZ = 64 * 32, BSZ = 128 * 32;   // shorts per buffer
    __shared__ __align__(16) unsigned short lA[2 * ASZ];
    __shared__ __align__(16) unsigned short lB[2 * BSZ];
    const int tid = threadIdx.x, w = tid >> 6, l = tid & 63;

    const int gx = gridDim.x;
    const int wg = xcd_remap(gx * gridDim.y, blockIdx.y * gx + blockIdx.x);
    const int m0 = (wg / gx) * 64, n0 = (wg % gx) * 128;

    const int wr = (w >> 2) * 32, wc = (w & 3) * 32;
    const int lr = l & 15, lk = (l >> 4) * 8;
    const int rsw = ((lr >> 1) & 3) << 4;
    // staging rows: A stripe (w&3) (only waves 0-3), B stripe w
    const int arow = (w & 3) * 16 + (l >> 2);
    const int brow = w * 16 + (l >> 2);
    const int gsA = (l & 3) ^ ((arow >> 1) & 3);
    const int gsB = (l & 3) ^ ((brow >> 1) & 3);

    f32x4 acc[2][2];
#pragma unroll
    for (int m = 0; m < 2; ++m)
#pragma unroll
        for (int n = 0; n < 2; ++n) acc[m][n] = (f32x4){0.f, 0.f, 0.f, 0.f};

    auto stage = [&](int k0, unsigned short* dA, unsigned short* dB) {
        if (w < 4)
            gload16(A + (size_t)(m0 + arow) * K + k0 + gsA * 8, dA + (w & 3) * 512);
        gload16(Bt + (size_t)(n0 + brow) * K + k0 + gsB * 8, dB + w * 512);
    };

    const int nt = K >> 5;
    stage(0, lA, lB);
    __syncthreads();

    for (int t = 0; t < nt; ++t) {
        unsigned short* cA = lA + (t & 1) * ASZ;
        unsigned short* cB = lB + (t & 1) * BSZ;
        if (t + 1 < nt)
            stage((t + 1) << 5, lA + ((t + 1) & 1) * ASZ, lB + ((t + 1) & 1) * BSZ);
        bf16x8 af[2], bfr[2];
#pragma unroll
        for (int m = 0; m < 2; ++m) {
            int row = wr + m * 16 + lr;
            af[m] = *(const bf16x8*)((const char*)cA + row * 64 + ((lk * 2) ^ rsw));
        }
#pragma unroll
        for (int n = 0; n < 2; ++n) {
            int row = wc + n * 16 + lr;
            bfr[n] = *(const bf16x8*)((const char*)cB + row * 64 + ((lk * 2) ^ rsw));
        }
#pragma unroll
        for (int m = 0; m < 2; ++m)
#pragma unroll
            for (int n = 0; n < 2; ++n)
                acc[m][n] = __builtin_amdgcn_mfma_f32_16x16x32_bf16(af[m], bfr[n], acc[m][n], 0, 0, 0);
        __syncthreads();
    }

    const int orow = (l >> 4) * 4, ocol = l & 15;
#pragma unroll
    for (int m = 0; m < 2; ++m)
#pragma unroll
        for (int n = 0; n < 2; ++n) {
            int c = n0 + wc + n * 16 + ocol;
            if (c >= N) continue;
            float bb = bias[c];
#pragma unroll
            for (int j = 0; j < 4; ++j) {
                int rr = m0 + wr + m * 16 + orow + j;
                float vv = acc[m][n][j] + bb;
                if (ACT_C == 1) vv = gelu_f(vv);
                if (ACT_C == 2) vv = fmaxf(vv, 0.f);
                Cm[(size_t)rr * ldC + c] = f2bf(vv);
            }
        }
}

// ---------------------------------------------------------------------------
// 64x64 GEMM, 512 threads / 8 waves (4x2 wave grid, wave tile 16x32), BK=64.
// (R14-proven.) ACT_C: 0 none, 1 gelu, 2 relu. K divisible by 64.
// ---------------------------------------------------------------------------
template<int ACT_C>
__launch_bounds__(512)
__global__ void gemm64(const unsigned short* __restrict__ A,
                       const unsigned short* __restrict__ Bt,
                       const float* __restrict__ bias,
                       unsigned short* __restrict__ Cm,
                       int M, int N, int K, int ldC) {
    constexpr int BUFS = 2 * 64 * 32;  // 4096 shorts per buffer (2 K-halves)
    __shared__ __align__(16) unsigned short lA[2 * BUFS];
    __shared__ __align__(16) unsigned short lB[2 * BUFS];
    const int tid = threadIdx.x, w = tid >> 6, l = tid & 63;

    const int gx = gridDim.x;
    const int wg = xcd_remap(gx * gridDim.y, blockIdx.y * gx + blockIdx.x);
    const int m0 = (wg / gx) * 64, n0 = (wg % gx) * 64;

    const int wr = (w >> 1) * 16, wc = (w & 1) * 32;   // 4x2 wave grid
    const int lr = l & 15, lk = (l >> 4) * 8;
    const int rsw = ((lr >> 1) & 3) << 4;
    const int sh = w >> 2;
    const int srow = (w & 3) * 16 + (l >> 2);
    const int sgs = (l & 3) ^ ((srow >> 1) & 3);

    f32x4 acc[2];
    acc[0] = (f32x4){0.f, 0.f, 0.f, 0.f};
    acc[1] = (f32x4){0.f, 0.f, 0.f, 0.f};

    auto stage = [&](int k0, unsigned short* dA, unsigned short* dB) {
        gload16(A + (size_t)(m0 + srow) * K + k0 + sh * 32 + sgs * 8, dA + w * 512);
        gload16(Bt + (size_t)(n0 + srow) * K + k0 + sh * 32 + sgs * 8, dB + w * 512);
    };

    const int nt = K >> 6;
    stage(0, lA, lB);
    __syncthreads();

    for (int t = 0; t < nt; ++t) {
        unsigned short* cA = lA + (t & 1) * BUFS;
        unsigned short* cB = lB + (t & 1) * BUFS;
        if (t + 1 < nt)
            stage((t + 1) << 6, lA + ((t + 1) & 1) * BUFS, lB + ((t + 1) & 1) * BUFS);
#pragma unroll
        for (int h = 0; h < 2; ++h) {
            bf16x8 af = *(const bf16x8*)((const char*)cA + h * 4096 +
                                         (wr + lr) * 64 + ((lk * 2) ^ rsw));
            bf16x8 b0 = *(const bf16x8*)((const char*)cB + h * 4096 +
                                         (wc + lr) * 64 + ((lk * 2) ^ rsw));
            bf16x8 b1 = *(const bf16x8*)((const char*)cB + h * 4096 +
                                         (wc + 16 + lr) * 64 + ((lk * 2) ^ rsw));
            acc[0] = __builtin_amdgcn_mfma_f32_16x16x32_bf16(af, b0, acc[0], 0, 0, 0);
            acc[1] = __builtin_amdgcn_mfma_f32_16x16x32_bf16(af, b1, acc[1], 0, 0, 0);
        }
        __syncthreads();
    }

    const int orow = (l >> 4) * 4, ocol = l & 15;
#pragma unroll
    for (int n = 0; n < 2; ++n) {
        int c = n0 + wc + n * 16 + ocol;
        if (c >= N) continue;
        float bb = bias[c];
#pragma unroll
        for (int j = 0; j < 4; ++j) {
            int rr = m0 + wr + orow + j;
            float vv = acc[n][j] + bb;
            if (ACT_C == 1) vv = gelu_f(vv);
            if (ACT_C == 2) vv = fmaxf(vv, 0.f);
            Cm[(size_t)rr * ldC + c] = f2bf(vv);
        }
    }
}

// ---------------------------------------------------------------------------
// FALLBACK GEMM (R2-proven): A bf16 x W f32 [K][N], converts W in-loop.
// ---------------------------------------------------------------------------
template<int ACT_A, int ACT_C>
__launch_bounds__(256)
__global__ void gemm_aw(const unsigned short* __restrict__ A,
                        const float* __restrict__ Wm,
                        const float* __restrict__ bias,
                        unsigned short* __restrict__ Cm,
                        int M, int N, int K, int ldC) {
    __shared__ __align__(16) unsigned short lA[64][40];
    __shared__ __align__(16) unsigned short lB[64][40];
    const int tid = threadIdx.x;
    const int m0 = blockIdx.y * 64;
    const int n0 = blockIdx.x * 64;
    const int w = tid >> 6, l = tid & 63;
    const int wr = (w >> 1) * 32, wc = (w & 1) * 32;
    const int lr = l & 15, lk = (l >> 4) * 8;

    f32x4 acc[2][2];
#pragma unroll
    for (int m = 0; m < 2; ++m)
#pragma unroll
        for (int n = 0; n < 2; ++n) acc[m][n] = (f32x4){0.f, 0.f, 0.f, 0.f};

    const int arow = tid >> 2, akc = (tid & 3) << 3;
    const int bkr = tid >> 3, bnc = (tid & 7) << 3;
    const bool nvec = (N & 7) == 0;

    for (int k0 = 0; k0 < K; k0 += 32) {
        uint4 av = *(const uint4*)(A + (size_t)(m0 + arow) * K + (k0 + akc));
        if (ACT_A) {
            unsigned short* p = (unsigned short*)&av;
#pragma unroll
            for (int j = 0; j < 8; ++j) if (p[j] & 0x8000u) p[j] = 0;
        }
        *(uint4*)&lA[arow][akc] = av;
        unsigned short bv[8];
        if (nvec) {
            const float* wp = Wm + (size_t)(k0 + bkr) * N + (n0 + bnc);
            float4 w0 = *(const float4*)(wp);
            float4 w1 = *(const float4*)(wp + 4);
            bv[0] = f2bf(w0.x); bv[1] = f2bf(w0.y); bv[2] = f2bf(w0.z); bv[3] = f2bf(w0.w);
            bv[4] = f2bf(w1.x); bv[5] = f2bf(w1.y); bv[6] = f2bf(w1.z); bv[7] = f2bf(w1.w);
        } else {
#pragma unroll
            for (int j = 0; j < 8; ++j) {
                int col = n0 + bnc + j;
                bv[j] = (col < N) ? f2bf(Wm[(size_t)(k0 + bkr) * N + col]) : (unsigned short)0;
            }
        }
#pragma unroll
        for (int j = 0; j < 8; ++j) lB[bnc + j][bkr] = bv[j];
        __syncthreads();

        bf16x8 af[2], bfr[2];
#pragma unroll
        for (int m = 0; m < 2; ++m) af[m] = *(const bf16x8*)&lA[wr + m * 16 + lr][lk];
#pragma unroll
        for (int n = 0; n < 2; ++n) bfr[n] = *(const bf16x8*)&lB[wc + n * 16 + lr][lk];
#pragma unroll
        for (int m = 0; m < 2; ++m)
#pragma unroll
            for (int n = 0; n < 2; ++n)
                acc[m][n] = __builtin_amdgcn_mfma_f32_16x16x32_bf16(af[m], bfr[n], acc[m][n], 0, 0, 0);
        __syncthreads();
    }

    const int orow = (l >> 4) * 4, ocol = l & 15;
#pragma unroll
    for (int m = 0; m < 2; ++m)
#pragma unroll
        for (int n = 0; n < 2; ++n) {
            int c = n0 + wc + n * 16 + ocol;
            if (c >= N) continue;
            float bb = bias[c];
#pragma unroll
            for (int j = 0; j < 4; ++j) {
                int r = m0 + wr + m * 16 + orow + j;
                float vv = acc[m][n][j] + bb;
                if (ACT_C == 1) vv = gelu_f(vv);
                if (ACT_C == 2) vv = fmaxf(vv, 0.f);
                Cm[(size_t)r * ldC + c] = f2bf(vv);
            }
        }
}

// ---------------------------------------------------------------------------
__global__ void transpose_w(const float* __restrict__ src, unsigned short* __restrict__ dst,
                            int K, int N, long srcLS, long dstLS) {
    int n0 = blockIdx.x * 32, k0 = blockIdx.y * 32;
    src += (size_t)blockIdx.z * srcLS;
    dst += (size_t)blockIdx.z * dstLS;
    __shared__ float tile[32][33];
    int tx = threadIdx.x & 31, ty = threadIdx.x >> 5;
#pragma unroll
    for (int r = 0; r < 4; ++r) {
        int k = k0 + ty + r * 8, n = n0 + tx;
        tile[ty + r * 8][tx] = (n < N && k < K) ? src[(size_t)k * N + n] : 0.f;
    }
    __syncthreads();
    int col2 = threadIdx.x & 15, rowb = threadIdx.x >> 4;
#pragma unroll
    for (int p = 0; p < 2; ++p) {
        int n = n0 + rowb + p * 16;
        unsigned int lo = f2bf(tile[col2 * 2][rowb + p * 16]);
        unsigned int hi = f2bf(tile[col2 * 2 + 1][rowb + p * 16]);
        *(unsigned int*)(dst + (size_t)n * K + k0 + col2 * 2) = lo | (hi << 16);
    }
}

__global__ void concat_bias(const float* bq, const float* bk, const float* bv, float* bqkv) {
    int i = blockIdx.x * 256 + threadIdx.x;
    if (i >= LL * QKVN) return;
    int lyr = i / QKVN, c = i % QKVN;
    float v = (c < HH) ? bq[lyr * HH + c] : (c < 2 * HH) ? bk[lyr * HH + c - HH] : bv[lyr * HH + c - 2 * HH];
    bqkv[i] = v;
}

__global__ void build_maskbias(const int* mask, float* mb) {
    int i = blockIdx.x * 256 + threadIdx.x;
    mb[i] = mask[i] ? 0.0f : -10000.0f;
}

// ---------------------------------------------------------------------------
// MFMA attention: one block per (qtile=64 rows, h, b). 256 thr = 4 waves.
// ---------------------------------------------------------------------------
__launch_bounds__(256)
__global__ void attention_mfma(const unsigned short* __restrict__ qkv,
                               const float* __restrict__ mb,
                               unsigned short* __restrict__ ctx) {
    const int qt = blockIdx.x, h = blockIdx.y, b = blockIdx.z;
    const int tid = threadIdx.x, w = tid >> 6, l = tid & 63;
    __shared__ __align__(16) unsigned short lK[SS * DHH];    // 32KB; reused as P[64][256]
    __shared__ __align__(16) unsigned short lVt[DHH * SS];   // 32KB
    const size_t tokbase = (size_t)b * SS * QKVN;

    {
        const unsigned short* kp = qkv + tokbase + (size_t)tid * QKVN + HH + h * DHH;
        const unsigned short* vp = kp + HH;
#pragma unroll
        for (int c = 0; c < 8; ++c) {
            uint4 kd = *(const uint4*)(kp + c * 8);
            *(uint4*)((char*)lK + ((tid * 128 + c * 16) ^ ((tid & 7) << 4))) = kd;
            uint4 vd = *(const uint4*)(vp + c * 8);
            const unsigned short* e = (const unsigned short*)&vd;
#pragma unroll
            for (int j = 0; j < 8; ++j) {
                int d = c * 8 + j;
                *(unsigned short*)((char*)lVt + ((d * 512 + tid * 2) ^ ((d & 7) << 4))) = e[j];
            }
        }
    }
    const int q0w = qt * 64 + w * 16;
    const unsigned short* qp = qkv + tokbase + (size_t)(q0w + (l & 15)) * QKVN + h * DHH + (l >> 4) * 8;
    bf16x8 aq0 = *(const bf16x8*)(qp);
    bf16x8 aq1 = *(const bf16x8*)(qp + 32);
    __syncthreads();

    f32x4 sc[16];
#pragma unroll
    for (int t = 0; t < 16; ++t) {
        int key = t * 16 + (l & 15);
        int base = key * 128;
        int sw = (key & 7) << 4;
        bf16x8 bk0 = *(const bf16x8*)((char*)lK + ((base + (l >> 4) * 16) ^ sw));
        bf16x8 bk1 = *(const bf16x8*)((char*)lK + ((base + 64 + (l >> 4) * 16) ^ sw));
        f32x4 a = (f32x4){0.f, 0.f, 0.f, 0.f};
        a = __builtin_amdgcn_mfma_f32_16x16x32_bf16(aq0, bk0, a, 0, 0, 0);
        a = __builtin_amdgcn_mfma_f32_16x16x32_bf16(aq1, bk1, a, 0, 0, 0);
        sc[t] = a;
    }
    const float* mbb = mb + b * SS;
    float mx[4] = {-3.0e38f, -3.0e38f, -3.0e38f, -3.0e38f};
#pragma unroll
    for (int t = 0; t < 16; ++t) {
        float mv = mbb[t * 16 + (l & 15)];
#pragma unroll
        for (int r = 0; r < 4; ++r) {
            float v = sc[t][r] * 0.125f + mv;
            sc[t][r] = v;
            mx[r] = fmaxf(mx[r], v);
        }
    }
#pragma unroll
    for (int m = 1; m <= 8; m <<= 1)
#pragma unroll
        for (int r = 0; r < 4; ++r) mx[r] = fmaxf(mx[r], __shfl_xor(mx[r], m));
    float sm[4] = {0.f, 0.f, 0.f, 0.f};
#pragma unroll
    for (int t = 0; t < 16; ++t)
#pragma unroll
        for (int r = 0; r < 4; ++r) {
            float e = __expf(sc[t][r] - mx[r]);
            sc[t][r] = e;
            sm[r] += e;
        }
#pragma unroll
    for (int m = 1; m <= 8; m <<= 1)
#pragma unroll
        for (int r = 0; r < 4; ++r) sm[r] += __shfl_xor(sm[r], m);
    float inv[4];
#pragma unroll
    for (int r = 0; r < 4; ++r) inv[r] = 1.0f / sm[r];

    __syncthreads();
    unsigned short* P = lK;
#pragma unroll
    for (int t = 0; t < 16; ++t)
#pragma unroll
        for (int r = 0; r < 4; ++r) {
            int prow = w * 16 + (l >> 4) * 4 + r;
            int pcol = t * 16 + (l & 15);
            *(unsigned short*)((char*)P + ((prow * 512 + pcol * 2) ^ ((prow & 7) << 4))) =
                f2bf(sc[t][r] * inv[r]);
        }
    __syncthreads();

    f32x4 o[4];
#pragma unroll
    for (int dt = 0; dt < 4; ++dt) o[dt] = (f32x4){0.f, 0.f, 0.f, 0.f};
#pragma unroll
    for (int kt = 0; kt < 8; ++kt) {
        int prow = w * 16 + (l & 15);
        int pkb = (kt * 32 + (l >> 4) * 8) * 2;
        bf16x8 pa = *(const bf16x8*)((char*)P + ((prow * 512 + pkb) ^ ((prow & 7) << 4)));
#pragma unroll
        for (int dt = 0; dt < 4; ++dt) {
            int d = dt * 16 + (l & 15);
            bf16x8 vb = *(const bf16x8*)((char*)lVt + ((d * 512 + pkb) ^ ((d & 7) << 4)));
            o[dt] = __builtin_amdgcn_mfma_f32_16x16x32_bf16(pa, vb, o[dt], 0, 0, 0);
        }
    }
#pragma unroll
    for (int dt = 0; dt < 4; ++dt)
#pragma unroll
        for (int r = 0; r < 4; ++r) {
            int q = qt * 64 + w * 16 + (l >> 4) * 4 + r;
            int d = dt * 16 + (l & 15);
            ctx[((size_t)(b * SS + q)) * HH + h * DHH + d] = f2bf(o[dt][r]);
        }
}

// ---------------------------------------------------------------------------
__global__ void embed_ln(const int* __restrict__ ids,
                         const float* __restrict__ we,
                         const float* __restrict__ pe,
                         const float* __restrict__ te,
                         const float* __restrict__ g,
                         const float* __restrict__ beta,
                         unsigned short* __restrict__ x) {
    int t = blockIdx.x, s = t % SS, tid = threadIdx.x;
    int id = ids[t];
    __shared__ float r1[256], r2[256];
    float e[3]; float sum = 0.f, sq = 0.f;
#pragma unroll
    for (int j = 0; j < 3; ++j) {
        int i = tid + j * 256;
        float v = we[(size_t)id * HH + i] + pe[(size_t)s * HH + i] + te[i];
        e[j] = v; sum += v; sq += v * v;
    }
    r1[tid] = sum; r2[tid] = sq; __syncthreads();
    for (int o = 128; o > 0; o >>= 1) {
        if (tid < o) { r1[tid] += r1[tid + o]; r2[tid] += r2[tid + o]; }
        __syncthreads();
    }
    float mu = r1[0] * (1.0f / HH);
    float var = fmaxf(r2[0] * (1.0f / HH) - mu * mu, 0.f);
    float rs = rsqrtf(var + 1e-12f);
#pragma unroll
    for (int j = 0; j < 3; ++j) {
        int i = tid + j * 256;
        x[(size_t)t * HH + i] = f2bf((e[j] - mu) * rs * g[i] + beta[i]);
    }
}

// ---------------------------------------------------------------------------
// x = LN(x + y): wave-per-token, no barriers. WRITE_RELU=1 also writes
// relu(result) to xr (feeds head GEMM, eliminates a separate relu pass).
// ---------------------------------------------------------------------------
template<int WRITE_RELU>
__launch_bounds__(256)
__global__ void add_ln(unsigned short* __restrict__ x,
                       const unsigned short* __restrict__ y,
                       const float* __restrict__ g,
                       const float* __restrict__ beta,
                       unsigned short* __restrict__ xr) {
    const int t = blockIdx.x * 4 + (threadIdx.x >> 6);
    const int l = threadIdx.x & 63;
    const size_t base = (size_t)t * HH;
    float v[12];
    float sum = 0.f, sq = 0.f;
#pragma unroll
    for (int j = 0; j < 3; ++j) {
        uint2 xa = *(const uint2*)(x + base + j * 256 + l * 4);
        uint2 ya = *(const uint2*)(y + base + j * 256 + l * 4);
        const unsigned short* xp = (const unsigned short*)&xa;
        const unsigned short* yp = (const unsigned short*)&ya;
#pragma unroll
        for (int e = 0; e < 4; ++e) {
            float vv = bf2f(xp[e]) + bf2f(yp[e]);
            v[j * 4 + e] = vv;
            sum += vv; sq += vv * vv;
        }
    }
#pragma unroll
    for (int m = 1; m < 64; m <<= 1) {
        sum += __shfl_xor(sum, m);
        sq += __shfl_xor(sq, m);
    }
    float mu = sum * (1.0f / HH);
    float var = fmaxf(sq * (1.0f / HH) - mu * mu, 0.f);
    float rs = rsqrtf(var + 1e-12f);
#pragma unroll
    for (int j = 0; j < 3; ++j) {
        float4 gg = *(const float4*)(g + j * 256 + l * 4);
        float4 bb = *(const float4*)(beta + j * 256 + l * 4);
        float r0 = (v[j * 4 + 0] - mu) * rs * gg.x + bb.x;
        float r1 = (v[j * 4 + 1] - mu) * rs * gg.y + bb.y;
        float r2 = (v[j * 4 + 2] - mu) * rs * gg.z + bb.z;
        float r3 = (v[j * 4 + 3] - mu) * rs * gg.w + bb.w;
        uint2 st = {(unsigned)f2bf(r0) | ((unsigned)f2bf(r1) << 16),
                    (unsigned)f2bf(r2) | ((unsigned)f2bf(r3) << 16)};
        *(uint2*)(x + base + j * 256 + l * 4) = st;
        if (WRITE_RELU) {
            uint2 sr = {(unsigned)f2bf(fmaxf(r0, 0.f)) | ((unsigned)f2bf(fmaxf(r1, 0.f)) << 16),
                        (unsigned)f2bf(fmaxf(r2, 0.f)) | ((unsigned)f2bf(fmaxf(r3, 0.f)) << 16)};
            *(uint2*)(xr + base + j * 256 + l * 4) = sr;
        }
    }
}

__global__ void cumsum_k(const int* __restrict__ wpt, int* __restrict__ cum) {
    int b = blockIdx.x, w = threadIdx.x;
    int s = 0;
    for (int j = 0; j <= w; ++j) s += wpt[b * WW + j];
    cum[b * WW + w] = s;
}

__global__ void pool_softmax(const unsigned short* __restrict__ f2,
                             const int* __restrict__ cum,
                             float* __restrict__ out) {
    int t = blockIdx.x, b = t / SS, s = t % SS, tid = threadIdx.x;
    __shared__ float red[512];
    float val = -1e30f;
    bool act = tid < CC;
    if (act) {
        if (s < WW) {
            int end = cum[b * WW + s];
            int start = s ? cum[b * WW + s - 1] : 0;
            float su = 0.f;
            for (int j = start; j < end; ++j) su += bf2f(f2[((size_t)b * SS + j) * CC + tid]);
            val = su / (float)(end - start);
        } else {
            val = bf2f(f2[((size_t)b * SS + s) * CC + tid]);
        }
    }
    red[tid] = val; __syncthreads();
    for (int o = 256; o > 0; o >>= 1) {
        if (tid < o) red[tid] = fmaxf(red[tid], red[tid + o]);
        __syncthreads();
    }
    float mx = red[0]; __syncthreads();
    float e = act ? expf(val - mx) : 0.f;
    red[tid] = e; __syncthreads();
    for (int o = 256; o > 0; o >>= 1) {
        if (tid < o) red[tid] += red[tid + o];
        __syncthreads();
    }
    float inv = 1.0f / red[0];
    if (act) out[((size_t)b * SS + s) * CC + tid] = e * inv;
}

// ---------------------------------------------------------------------------
static inline size_t al256(size_t x) { return (x + 255) & ~(size_t)255; }

extern "C" void kernel_launch(void* const* d_in, const int* in_sizes, int n_in,
                              void* d_out, int out_size, void* d_ws, size_t ws_size,
                              hipStream_t stream) {
    const int* enc   = (const int*)d_in[0];
    const int* mask  = (const int*)d_in[1];
    const int* wpt   = (const int*)d_in[2];
    const float* word_emb = (const float*)d_in[3];
    const float* pos_emb  = (const float*)d_in[4];
    const float* type_emb = (const float*)d_in[5];
    const float* eln_s = (const float*)d_in[6];
    const float* eln_b = (const float*)d_in[7];
    const float* Wq = (const float*)d_in[8];
    const float* bq = (const float*)d_in[9];
    const float* Wk = (const float*)d_in[10];
    const float* bk = (const float*)d_in[11];
    const float* Wv = (const float*)d_in[12];
    const float* bv = (const float*)d_in[13];
    const float* Wo = (const float*)d_in[14];
    const float* bo = (const float*)d_in[15];
    const float* ln1s = (const float*)d_in[16];
    const float* ln1b = (const float*)d_in[17];
    const float* Wi = (const float*)d_in[18];
    const float* bi = (const float*)d_in[19];
    const float* Wo2 = (const float*)d_in[20];
    const float* bo2 = (const float*)d_in[21];
    const float* ln2s = (const float*)d_in[22];
    const float* ln2b = (const float*)d_in[23];
    const float* w1 = (const float*)d_in[24];
    const float* b1 = (const float*)d_in[25];
    const float* w2 = (const float*)d_in[26];
    const float* b2 = (const float*)d_in[27];

    unsigned char* ws = (unsigned char*)d_ws;
    size_t off = 0;
    unsigned short* x    = (unsigned short*)(ws + off); off = al256(off + (size_t)NTOK * HH * 2);
    unsigned short* qkv  = (unsigned short*)(ws + off); off = al256(off + (size_t)NTOK * QKVN * 2);
    unsigned short* ctx  = (unsigned short*)(ws + off); off = al256(off + (size_t)NTOK * HH * 2);
    unsigned short* proj = (unsigned short*)(ws + off); off = al256(off + (size_t)NTOK * HH * 2);
    unsigned short* ff   = (unsigned short*)(ws + off); off = al256(off + (size_t)NTOK * FFD * 2);
    unsigned short* f1   = (unsigned short*)(ws + off); off = al256(off + (size_t)NTOK * 1024 * 2);
    unsigned short* f2   = (unsigned short*)(ws + off); off = al256(off + (size_t)NTOK * CC * 2);
    unsigned short* xr   = (unsigned short*)(ws + off); off = al256(off + (size_t)NTOK * HH * 2);
    float* mb            = (float*)(ws + off);          off = al256(off + (size_t)NTOK * 4);
    int* cum             = (int*)(ws + off);            off = al256(off + (size_t)BB * WW * 4);
    float* bqkv          = (float*)(ws + off);          off = al256(off + (size_t)LL * QKVN * 4);
    size_t offFast = off;
    unsigned short* WqkvT = (unsigned short*)(ws + offFast); offFast = al256(offFast + (size_t)LL * QKVN * HH * 2);
    unsigned short* WoT   = (unsigned short*)(ws + offFast); offFast = al256(offFast + (size_t)LL * HH * HH * 2);
    unsigned short* WiT   = (unsigned short*)(ws + offFast); offFast = al256(offFast + (size_t)LL * FFD * HH * 2);
    unsigned short* Wo2T  = (unsigned short*)(ws + offFast); offFast = al256(offFast + (size_t)LL * HH * FFD * 2);
    unsigned short* w1T   = (unsigned short*)(ws + offFast); offFast = al256(offFast + (size_t)1024 * HH * 2);
    unsigned short* w2T   = (unsigned short*)(ws + offFast); offFast = al256(offFast + (size_t)512 * 1024 * 2);
    const bool fast = (ws_size >= offFast);

    build_maskbias<<<NTOK / 256, 256, 0, stream>>>(mask, mb);
    concat_bias<<<(LL * QKVN + 255) / 256, 256, 0, stream>>>(bq, bk, bv, bqkv);

    if (fast) {
        transpose_w<<<dim3(24, 24, LL), 256, 0, stream>>>(Wq, WqkvT, HH, HH, (long)HH * HH, (long)QKVN * HH);
        transpose_w<<<dim3(24, 24, LL), 256, 0, stream>>>(Wk, WqkvT + (size_t)HH * HH, HH, HH, (long)HH * HH, (long)QKVN * HH);
        transpose_w<<<dim3(24, 24, LL), 256, 0, stream>>>(Wv, WqkvT + (size_t)2 * HH * HH, HH, HH, (long)HH * HH, (long)QKVN * HH);
        transpose_w<<<dim3(24, 24, LL), 256, 0, stream>>>(Wo, WoT, HH, HH, (long)HH * HH, (long)HH * HH);
        transpose_w<<<dim3(96, 24, LL), 256, 0, stream>>>(Wi, WiT, HH, FFD, (long)HH * FFD, (long)FFD * HH);
        transpose_w<<<dim3(24, 96, LL), 256, 0, stream>>>(Wo2, Wo2T, FFD, HH, (long)FFD * HH, (long)HH * FFD);
        transpose_w<<<dim3(32, 24, 1), 256, 0, stream>>>(w1, w1T, HH, 1024, 0, 0);
        transpose_w<<<dim3(16, 32, 1), 256, 0, stream>>>(w2, w2T, 1024, CC, 0, 0);
    }

    embed_ln<<<NTOK, 256, 0, stream>>>(enc, word_emb, pos_emb, type_emb, eln_s, eln_b, x);

    const dim3 gQKV(QKVN / 128, NTOK / 64);     // 1152 blocks, 64x128 (512 thr, 32 waves/CU)
    const dim3 gWo(HH / 64, NTOK / 64);         // 768 blocks, 64x64 BK64 (512 thr)
    const dim3 gFF1(FFD / 128, NTOK / 128);     // 768 blocks, 128x128 (512 thr)
    const dim3 gFF2(HH / 64, NTOK / 64);        // 768 blocks, 64x64 BK64 (512 thr)
    const dim3 gH1(1024 / 64, NTOK / 64);       // 1024 blocks, 64x64 BK64 (512 thr)
    const dim3 gH2(7, NTOK / 64);               // 448 blocks, 64x64 BK64 (512 thr)
    const dim3 gAttn(4, NHH, BB);

    for (int l = 0; l < LL; ++l) {
        if (fast) {
            gemm64x128<0><<<gQKV, 512, 0, stream>>>(x, WqkvT + (size_t)l * QKVN * HH, bqkv + l * QKVN, qkv, NTOK, QKVN, HH, QKVN);
        } else {
            const dim3 g64(HH / 64, NTOK / 64);
            gemm_aw<0, 0><<<g64, 256, 0, stream>>>(x, Wq + (size_t)l * HH * HH, bq + l * HH, qkv, NTOK, HH, HH, QKVN);
            gemm_aw<0, 0><<<g64, 256, 0, stream>>>(x, Wk + (size_t)l * HH * HH, bk + l * HH, qkv + HH, NTOK, HH, HH, QKVN);
            gemm_aw<0, 0><<<g64, 256, 0, stream>>>(x, Wv + (size_t)l * HH * HH, bv + l * HH, qkv + 2 * HH, NTOK, HH, HH, QKVN);
        }
        attention_mfma<<<gAttn, 256, 0, stream>>>(qkv, mb, ctx);
        if (fast) {
            gemm64<0><<<gWo, 512, 0, stream>>>(ctx, WoT + (size_t)l * HH * HH, bo + l * HH, proj, NTOK, HH, HH, HH);
        } else {
            gemm_aw<0, 0><<<dim3(HH / 64, NTOK / 64), 256, 0, stream>>>(ctx, Wo + (size_t)l * HH * HH, bo + l * HH, proj, NTOK, HH, HH, HH);
        }
        add_ln<0><<<NTOK / 4, 256, 0, stream>>>(x, proj, ln1s + l * HH, ln1b + l * HH, nullptr);
        if (fast) {
            gemm128<1><<<gFF1, 512, 0, stream>>>(x, WiT + (size_t)l * FFD * HH, bi + l * FFD, ff, NTOK, FFD, HH, FFD);
            gemm64<0><<<gFF2, 512, 0, stream>>>(ff, Wo2T + (size_t)l * HH * FFD, bo2 + l * HH, proj, NTOK, HH, FFD, HH);
        } else {
            gemm_aw<0, 1><<<dim3(FFD / 64, NTOK / 64), 256, 0, stream>>>(x, Wi + (size_t)l * HH * FFD, bi + l * FFD, ff, NTOK, FFD, HH, FFD);
            gemm_aw<0, 0><<<dim3(HH / 64, NTOK / 64), 256, 0, stream>>>(ff, Wo2 + (size_t)l * FFD * HH, bo2 + l * HH, proj, NTOK, HH, FFD, HH);
        }
        if (l == LL - 1)
            add_ln<1><<<NTOK / 4, 256, 0, stream>>>(x, proj, ln2s + l * HH, ln2b + l * HH, xr);
        else
            add_ln<0><<<NTOK / 4, 256, 0, stream>>>(x, proj, ln2s + l * HH, ln2b + l * HH, nullptr);
    }

    // head: H1 fuses relu into epilogue (f1 = relu(xr@w1+b1)); H2 plain.
    if (fast) {
        gemm64<2><<<gH1, 512, 0, stream>>>(xr, w1T, b1, f1, NTOK, 1024, HH, 1024);
        gemm64<0><<<gH2, 512, 0, stream>>>(f1, w2T, b2, f2, NTOK, CC, 1024, CC);
    } else {
        gemm_aw<0, 2><<<dim3(1024 / 64, NTOK / 64), 256, 0, stream>>>(xr, w1, b1, f1, NTOK, 1024, HH, 1024);
        gemm_aw<0, 0><<<dim3(7, NTOK / 64), 256, 0, stream>>>(f1, w2, b2, f2, NTOK, CC, 1024, CC);
    }
    cumsum_k<<<BB, WW, 0, stream>>>(wpt, cum);
    pool_softmax<<<NTOK, 512, 0, stream>>>(f2, cum, (float*)d_out);
}

// Round 17
// 1942.946 us; speedup vs baseline: 1.0768x; 1.0768x over previous
//
#include <hip/hip_runtime.h>
#include <math.h>

#define BB 16
#define SS 256
#define WW 128
#define HH 768
#define LL 12
#define NHH 12
#define DHH 64
#define FFD 3072
#define CC 425
#define NTOK (BB*SS)
#define QKVN (3*HH)   // 2304

typedef __attribute__((ext_vector_type(8))) short bf16x8;
typedef __attribute__((ext_vector_type(4))) float f32x4;

__device__ __forceinline__ float bf2f(unsigned short u) {
    union { unsigned int i; float f; } z; z.i = ((unsigned int)u) << 16; return z.f;
}
__device__ __forceinline__ unsigned short f2bf(float f) {
    union { float f; unsigned int i; } z; z.f = f;
    unsigned int i = z.i;
    unsigned int r = (i + 0x7fffu + ((i >> 16) & 1u)) >> 16;
    return (unsigned short)r;
}

__device__ __forceinline__ void gload16(const void* g, void* l) {
    __builtin_amdgcn_global_load_lds((const __attribute__((address_space(1))) void*)g,
                                     (__attribute__((address_space(3))) void*)l, 16, 0, 0);
}

// Explicit drain of global_load_lds traffic before a barrier. The 2-phase
// pipeline's correctness REQUIRES all gload_lds writes to LDS to be resident
// before any wave crosses the barrier; the compiler usually emits this drain
// for __syncthreads, but we make it explicit (free if already drained) after
// R16's timing-dependent post-replay divergence implicated a missed drain.
__device__ __forceinline__ void drain_vm() {
    asm volatile("s_waitcnt vmcnt(0)" ::: "memory");
}

// gelu via A&S 7.1.26 erf (|err|<=1.5e-7, invisible at bf16) + __expf
__device__ __forceinline__ float gelu_f(float v) {
    float ax = fabsf(v) * 0.70710678118654752f;
    float t = 1.0f / fmaf(0.3275911f, ax, 1.0f);
    float poly = t * fmaf(t, fmaf(t, fmaf(t, fmaf(t, 1.061405429f, -1.453152027f),
                                          1.421413741f), -0.284496736f), 0.254829592f);
    float er = 1.0f - poly * __expf(-ax * ax);
    er = (v < 0.f) ? -er : er;
    return 0.5f * v * (1.0f + er);
}

__device__ __forceinline__ int xcd_remap(int nwg, int orig) {
    int q = nwg >> 3, r = nwg & 7, xc = orig & 7, o8 = orig >> 3;
    return (xc < r ? xc * (q + 1) : r * (q + 1) + (xc - r) * q) + o8;
}

// ---------------------------------------------------------------------------
// 128x128 GEMM, 512 threads / 8 waves (wave tile 64x32), 2-phase dbuf,
// explicit vmcnt(0) drain before each barrier (race-hardened).
// LDS rows 64B; slot swizzle g ^ ((row>>1)&3) (conflict-free, R5-verified).
// ACT_C: 0 none, 1 gelu, 2 relu.
// ---------------------------------------------------------------------------
template<int ACT_C>
__launch_bounds__(512)
__global__ void gemm128(const unsigned short* __restrict__ A,
                        const unsigned short* __restrict__ Bt,
                        const float* __restrict__ bias,
                        unsigned short* __restrict__ Cm,
                        int M, int N, int K, int ldC) {
    constexpr int BUFS = 128 * 32;   // shorts per buffer
    __shared__ __align__(16) unsigned short lA[2 * BUFS];
    __shared__ __align__(16) unsigned short lB[2 * BUFS];
    const int tid = threadIdx.x, w = tid >> 6, l = tid & 63;

    const int gx = gridDim.x;
    const int wg = xcd_remap(gx * gridDim.y, blockIdx.y * gx + blockIdx.x);
    const int m0 = (wg / gx) * 128, n0 = (wg % gx) * 128;

    const int wr = (w >> 2) * 64, wc = (w & 3) * 32;
    const int lr = l & 15, lk = (l >> 4) * 8;
    const int rsw = ((lr >> 1) & 3) << 4;
    const int lrow = l >> 2;
    const int gs = (l & 3) ^ ((lrow >> 1) & 3);

    f32x4 acc[4][2];
#pragma unroll
    for (int m = 0; m < 4; ++m)
#pragma unroll
        for (int n = 0; n < 2; ++n) acc[m][n] = (f32x4){0.f, 0.f, 0.f, 0.f};

    auto stage = [&](int k0, unsigned short* dA, unsigned short* dB) {
        gload16(A + (size_t)(m0 + w * 16 + lrow) * K + k0 + gs * 8, dA + w * 512);
        gload16(Bt + (size_t)(n0 + w * 16 + lrow) * K + k0 + gs * 8, dB + w * 512);
    };

    const int nt = K >> 5;
    stage(0, lA, lB);
    drain_vm();
    __syncthreads();

    for (int t = 0; t < nt; ++t) {
        unsigned short* cA = lA + (t & 1) * BUFS;
        unsigned short* cB = lB + (t & 1) * BUFS;
        if (t + 1 < nt)
            stage((t + 1) << 5, lA + ((t + 1) & 1) * BUFS, lB + ((t + 1) & 1) * BUFS);
        bf16x8 af[4], bfr[2];
#pragma unroll
        for (int m = 0; m < 4; ++m) {
            int row = wr + m * 16 + lr;
            af[m] = *(const bf16x8*)((const char*)cA + row * 64 + ((lk * 2) ^ rsw));
        }
#pragma unroll
        for (int n = 0; n < 2; ++n) {
            int row = wc + n * 16 + lr;
            bfr[n] = *(const bf16x8*)((const char*)cB + row * 64 + ((lk * 2) ^ rsw));
        }
#pragma unroll
        for (int m = 0; m < 4; ++m)
#pragma unroll
            for (int n = 0; n < 2; ++n)
                acc[m][n] = __builtin_amdgcn_mfma_f32_16x16x32_bf16(af[m], bfr[n], acc[m][n], 0, 0, 0);
        drain_vm();            // staged tile t+1 fully resident before barrier
        __syncthreads();
    }

    const int orow = (l >> 4) * 4, ocol = l & 15;
#pragma unroll
    for (int m = 0; m < 4; ++m)
#pragma unroll
        for (int n = 0; n < 2; ++n) {
            int c = n0 + wc + n * 16 + ocol;
            if (c >= N) continue;
            float bb = bias[c];
#pragma unroll
            for (int j = 0; j < 4; ++j) {
                int rr = m0 + wr + m * 16 + orow + j;
                float vv = acc[m][n][j] + bb;
                if (ACT_C == 1) vv = gelu_f(vv);
                if (ACT_C == 2) vv = fmaxf(vv, 0.f);
                Cm[(size_t)rr * ldC + c] = f2bf(vv);
            }
        }
}

// ---------------------------------------------------------------------------
// 64x64 GEMM, 512 threads / 8 waves (4x2 wave grid, wave tile 16x32), BK=64,
// explicit vmcnt(0) drain before each barrier (race-hardened).
// ACT_C: 0 none, 1 gelu, 2 relu. K divisible by 64.
// ---------------------------------------------------------------------------
template<int ACT_C>
__launch_bounds__(512)
__global__ void gemm64(const unsigned short* __restrict__ A,
                       const unsigned short* __restrict__ Bt,
                       const float* __restrict__ bias,
                       unsigned short* __restrict__ Cm,
                       int M, int N, int K, int ldC) {
    constexpr int BUFS = 2 * 64 * 32;  // 4096 shorts per buffer (2 K-halves)
    __shared__ __align__(16) unsigned short lA[2 * BUFS];
    __shared__ __align__(16) unsigned short lB[2 * BUFS];
    const int tid = threadIdx.x, w = tid >> 6, l = tid & 63;

    const int gx = gridDim.x;
    const int wg = xcd_remap(gx * gridDim.y, blockIdx.y * gx + blockIdx.x);
    const int m0 = (wg / gx) * 64, n0 = (wg % gx) * 64;

    const int wr = (w >> 1) * 16, wc = (w & 1) * 32;   // 4x2 wave grid
    const int lr = l & 15, lk = (l >> 4) * 8;
    const int rsw = ((lr >> 1) & 3) << 4;
    const int sh = w >> 2;
    const int srow = (w & 3) * 16 + (l >> 2);
    const int sgs = (l & 3) ^ ((srow >> 1) & 3);

    f32x4 acc[2];
    acc[0] = (f32x4){0.f, 0.f, 0.f, 0.f};
    acc[1] = (f32x4){0.f, 0.f, 0.f, 0.f};

    auto stage = [&](int k0, unsigned short* dA, unsigned short* dB) {
        gload16(A + (size_t)(m0 + srow) * K + k0 + sh * 32 + sgs * 8, dA + w * 512);
        gload16(Bt + (size_t)(n0 + srow) * K + k0 + sh * 32 + sgs * 8, dB + w * 512);
    };

    const int nt = K >> 6;
    stage(0, lA, lB);
    drain_vm();
    __syncthreads();

    for (int t = 0; t < nt; ++t) {
        unsigned short* cA = lA + (t & 1) * BUFS;
        unsigned short* cB = lB + (t & 1) * BUFS;
        if (t + 1 < nt)
            stage((t + 1) << 6, lA + ((t + 1) & 1) * BUFS, lB + ((t + 1) & 1) * BUFS);
#pragma unroll
        for (int h = 0; h < 2; ++h) {
            bf16x8 af = *(const bf16x8*)((const char*)cA + h * 4096 +
                                         (wr + lr) * 64 + ((lk * 2) ^ rsw));
            bf16x8 b0 = *(const bf16x8*)((const char*)cB + h * 4096 +
                                         (wc + lr) * 64 + ((lk * 2) ^ rsw));
            bf16x8 b1 = *(const bf16x8*)((const char*)cB + h * 4096 +
                                         (wc + 16 + lr) * 64 + ((lk * 2) ^ rsw));
            acc[0] = __builtin_amdgcn_mfma_f32_16x16x32_bf16(af, b0, acc[0], 0, 0, 0);
            acc[1] = __builtin_amdgcn_mfma_f32_16x16x32_bf16(af, b1, acc[1], 0, 0, 0);
        }
        drain_vm();            // staged tile t+1 fully resident before barrier
        __syncthreads();
    }

    const int orow = (l >> 4) * 4, ocol = l & 15;
#pragma unroll
    for (int n = 0; n < 2; ++n) {
        int c = n0 + wc + n * 16 + ocol;
        if (c >= N) continue;
        float bb = bias[c];
#pragma unroll
        for (int j = 0; j < 4; ++j) {
            int rr = m0 + wr + orow + j;
            float vv = acc[n][j] + bb;
            if (ACT_C == 1) vv = gelu_f(vv);
            if (ACT_C == 2) vv = fmaxf(vv, 0.f);
            Cm[(size_t)rr * ldC + c] = f2bf(vv);
        }
    }
}

// ---------------------------------------------------------------------------
// FALLBACK GEMM (R2-proven): A bf16 x W f32 [K][N], converts W in-loop.
// ---------------------------------------------------------------------------
template<int ACT_A, int ACT_C>
__launch_bounds__(256)
__global__ void gemm_aw(const unsigned short* __restrict__ A,
                        const float* __restrict__ Wm,
                        const float* __restrict__ bias,
                        unsigned short* __restrict__ Cm,
                        int M, int N, int K, int ldC) {
    __shared__ __align__(16) unsigned short lA[64][40];
    __shared__ __align__(16) unsigned short lB[64][40];
    const int tid = threadIdx.x;
    const int m0 = blockIdx.y * 64;
    const int n0 = blockIdx.x * 64;
    const int w = tid >> 6, l = tid & 63;
    const int wr = (w >> 1) * 32, wc = (w & 1) * 32;
    const int lr = l & 15, lk = (l >> 4) * 8;

    f32x4 acc[2][2];
#pragma unroll
    for (int m = 0; m < 2; ++m)
#pragma unroll
        for (int n = 0; n < 2; ++n) acc[m][n] = (f32x4){0.f, 0.f, 0.f, 0.f};

    const int arow = tid >> 2, akc = (tid & 3) << 3;
    const int bkr = tid >> 3, bnc = (tid & 7) << 3;
    const bool nvec = (N & 7) == 0;

    for (int k0 = 0; k0 < K; k0 += 32) {
        uint4 av = *(const uint4*)(A + (size_t)(m0 + arow) * K + (k0 + akc));
        if (ACT_A) {
            unsigned short* p = (unsigned short*)&av;
#pragma unroll
            for (int j = 0; j < 8; ++j) if (p[j] & 0x8000u) p[j] = 0;
        }
        *(uint4*)&lA[arow][akc] = av;
        unsigned short bv[8];
        if (nvec) {
            const float* wp = Wm + (size_t)(k0 + bkr) * N + (n0 + bnc);
            float4 w0 = *(const float4*)(wp);
            float4 w1 = *(const float4*)(wp + 4);
            bv[0] = f2bf(w0.x); bv[1] = f2bf(w0.y); bv[2] = f2bf(w0.z); bv[3] = f2bf(w0.w);
            bv[4] = f2bf(w1.x); bv[5] = f2bf(w1.y); bv[6] = f2bf(w1.z); bv[7] = f2bf(w1.w);
        } else {
#pragma unroll
            for (int j = 0; j < 8; ++j) {
                int col = n0 + bnc + j;
                bv[j] = (col < N) ? f2bf(Wm[(size_t)(k0 + bkr) * N + col]) : (unsigned short)0;
            }
        }
#pragma unroll
        for (int j = 0; j < 8; ++j) lB[bnc + j][bkr] = bv[j];
        __syncthreads();

        bf16x8 af[2], bfr[2];
#pragma unroll
        for (int m = 0; m < 2; ++m) af[m] = *(const bf16x8*)&lA[wr + m * 16 + lr][lk];
#pragma unroll
        for (int n = 0; n < 2; ++n) bfr[n] = *(const bf16x8*)&lB[wc + n * 16 + lr][lk];
#pragma unroll
        for (int m = 0; m < 2; ++m)
#pragma unroll
            for (int n = 0; n < 2; ++n)
                acc[m][n] = __builtin_amdgcn_mfma_f32_16x16x32_bf16(af[m], bfr[n], acc[m][n], 0, 0, 0);
        __syncthreads();
    }

    const int orow = (l >> 4) * 4, ocol = l & 15;
#pragma unroll
    for (int m = 0; m < 2; ++m)
#pragma unroll
        for (int n = 0; n < 2; ++n) {
            int c = n0 + wc + n * 16 + ocol;
            if (c >= N) continue;
            float bb = bias[c];
#pragma unroll
            for (int j = 0; j < 4; ++j) {
                int r = m0 + wr + m * 16 + orow + j;
                float vv = acc[m][n][j] + bb;
                if (ACT_C == 1) vv = gelu_f(vv);
                if (ACT_C == 2) vv = fmaxf(vv, 0.f);
                Cm[(size_t)r * ldC + c] = f2bf(vv);
            }
        }
}

// ---------------------------------------------------------------------------
__global__ void transpose_w(const float* __restrict__ src, unsigned short* __restrict__ dst,
                            int K, int N, long srcLS, long dstLS) {
    int n0 = blockIdx.x * 32, k0 = blockIdx.y * 32;
    src += (size_t)blockIdx.z * srcLS;
    dst += (size_t)blockIdx.z * dstLS;
    __shared__ float tile[32][33];
    int tx = threadIdx.x & 31, ty = threadIdx.x >> 5;
#pragma unroll
    for (int r = 0; r < 4; ++r) {
        int k = k0 + ty + r * 8, n = n0 + tx;
        tile[ty + r * 8][tx] = (n < N && k < K) ? src[(size_t)k * N + n] : 0.f;
    }
    __syncthreads();
    int col2 = threadIdx.x & 15, rowb = threadIdx.x >> 4;
#pragma unroll
    for (int p = 0; p < 2; ++p) {
        int n = n0 + rowb + p * 16;
        unsigned int lo = f2bf(tile[col2 * 2][rowb + p * 16]);
        unsigned int hi = f2bf(tile[col2 * 2 + 1][rowb + p * 16]);
        *(unsigned int*)(dst + (size_t)n * K + k0 + col2 * 2) = lo | (hi << 16);
    }
}

__global__ void concat_bias(const float* bq, const float* bk, const float* bv, float* bqkv) {
    int i = blockIdx.x * 256 + threadIdx.x;
    if (i >= LL * QKVN) return;
    int lyr = i / QKVN, c = i % QKVN;
    float v = (c < HH) ? bq[lyr * HH + c] : (c < 2 * HH) ? bk[lyr * HH + c - HH] : bv[lyr * HH + c - 2 * HH];
    bqkv[i] = v;
}

__global__ void build_maskbias(const int* mask, float* mb) {
    int i = blockIdx.x * 256 + threadIdx.x;
    mb[i] = mask[i] ? 0.0f : -10000.0f;
}

// ---------------------------------------------------------------------------
// MFMA attention: one block per (qtile=64 rows, h, b). 256 thr = 4 waves.
// (Plain ds_write staging; standard __syncthreads ordering applies.)
// ---------------------------------------------------------------------------
__launch_bounds__(256)
__global__ void attention_mfma(const unsigned short* __restrict__ qkv,
                               const float* __restrict__ mb,
                               unsigned short* __restrict__ ctx) {
    const int qt = blockIdx.x, h = blockIdx.y, b = blockIdx.z;
    const int tid = threadIdx.x, w = tid >> 6, l = tid & 63;
    __shared__ __align__(16) unsigned short lK[SS * DHH];    // 32KB; reused as P[64][256]
    __shared__ __align__(16) unsigned short lVt[DHH * SS];   // 32KB
    const size_t tokbase = (size_t)b * SS * QKVN;

    {
        const unsigned short* kp = qkv + tokbase + (size_t)tid * QKVN + HH + h * DHH;
        const unsigned short* vp = kp + HH;
#pragma unroll
        for (int c = 0; c < 8; ++c) {
            uint4 kd = *(const uint4*)(kp + c * 8);
            *(uint4*)((char*)lK + ((tid * 128 + c * 16) ^ ((tid & 7) << 4))) = kd;
            uint4 vd = *(const uint4*)(vp + c * 8);
            const unsigned short* e = (const unsigned short*)&vd;
#pragma unroll
            for (int j = 0; j < 8; ++j) {
                int d = c * 8 + j;
                *(unsigned short*)((char*)lVt + ((d * 512 + tid * 2) ^ ((d & 7) << 4))) = e[j];
            }
        }
    }
    const int q0w = qt * 64 + w * 16;
    const unsigned short* qp = qkv + tokbase + (size_t)(q0w + (l & 15)) * QKVN + h * DHH + (l >> 4) * 8;
    bf16x8 aq0 = *(const bf16x8*)(qp);
    bf16x8 aq1 = *(const bf16x8*)(qp + 32);
    __syncthreads();

    f32x4 sc[16];
#pragma unroll
    for (int t = 0; t < 16; ++t) {
        int key = t * 16 + (l & 15);
        int base = key * 128;
        int sw = (key & 7) << 4;
        bf16x8 bk0 = *(const bf16x8*)((char*)lK + ((base + (l >> 4) * 16) ^ sw));
        bf16x8 bk1 = *(const bf16x8*)((char*)lK + ((base + 64 + (l >> 4) * 16) ^ sw));
        f32x4 a = (f32x4){0.f, 0.f, 0.f, 0.f};
        a = __builtin_amdgcn_mfma_f32_16x16x32_bf16(aq0, bk0, a, 0, 0, 0);
        a = __builtin_amdgcn_mfma_f32_16x16x32_bf16(aq1, bk1, a, 0, 0, 0);
        sc[t] = a;
    }
    const float* mbb = mb + b * SS;
    float mx[4] = {-3.0e38f, -3.0e38f, -3.0e38f, -3.0e38f};
#pragma unroll
    for (int t = 0; t < 16; ++t) {
        float mv = mbb[t * 16 + (l & 15)];
#pragma unroll
        for (int r = 0; r < 4; ++r) {
            float v = sc[t][r] * 0.125f + mv;
            sc[t][r] = v;
            mx[r] = fmaxf(mx[r], v);
        }
    }
#pragma unroll
    for (int m = 1; m <= 8; m <<= 1)
#pragma unroll
        for (int r = 0; r < 4; ++r) mx[r] = fmaxf(mx[r], __shfl_xor(mx[r], m));
    float sm[4] = {0.f, 0.f, 0.f, 0.f};
#pragma unroll
    for (int t = 0; t < 16; ++t)
#pragma unroll
        for (int r = 0; r < 4; ++r) {
            float e = __expf(sc[t][r] - mx[r]);
            sc[t][r] = e;
            sm[r] += e;
        }
#pragma unroll
    for (int m = 1; m <= 8; m <<= 1)
#pragma unroll
        for (int r = 0; r < 4; ++r) sm[r] += __shfl_xor(sm[r], m);
    float inv[4];
#pragma unroll
    for (int r = 0; r < 4; ++r) inv[r] = 1.0f / sm[r];

    __syncthreads();
    unsigned short* P = lK;
#pragma unroll
    for (int t = 0; t < 16; ++t)
#pragma unroll
        for (int r = 0; r < 4; ++r) {
            int prow = w * 16 + (l >> 4) * 4 + r;
            int pcol = t * 16 + (l & 15);
            *(unsigned short*)((char*)P + ((prow * 512 + pcol * 2) ^ ((prow & 7) << 4))) =
                f2bf(sc[t][r] * inv[r]);
        }
    __syncthreads();

    f32x4 o[4];
#pragma unroll
    for (int dt = 0; dt < 4; ++dt) o[dt] = (f32x4){0.f, 0.f, 0.f, 0.f};
#pragma unroll
    for (int kt = 0; kt < 8; ++kt) {
        int prow = w * 16 + (l & 15);
        int pkb = (kt * 32 + (l >> 4) * 8) * 2;
        bf16x8 pa = *(const bf16x8*)((char*)P + ((prow * 512 + pkb) ^ ((prow & 7) << 4)));
#pragma unroll
        for (int dt = 0; dt < 4; ++dt) {
            int d = dt * 16 + (l & 15);
            bf16x8 vb = *(const bf16x8*)((char*)lVt + ((d * 512 + pkb) ^ ((d & 7) << 4)));
            o[dt] = __builtin_amdgcn_mfma_f32_16x16x32_bf16(pa, vb, o[dt], 0, 0, 0);
        }
    }
#pragma unroll
    for (int dt = 0; dt < 4; ++dt)
#pragma unroll
        for (int r = 0; r < 4; ++r) {
            int q = qt * 64 + w * 16 + (l >> 4) * 4 + r;
            int d = dt * 16 + (l & 15);
            ctx[((size_t)(b * SS + q)) * HH + h * DHH + d] = f2bf(o[dt][r]);
        }
}

// ---------------------------------------------------------------------------
__global__ void embed_ln(const int* __restrict__ ids,
                         const float* __restrict__ we,
                         const float* __restrict__ pe,
                         const float* __restrict__ te,
                         const float* __restrict__ g,
                         const float* __restrict__ beta,
                         unsigned short* __restrict__ x) {
    int t = blockIdx.x, s = t % SS, tid = threadIdx.x;
    int id = ids[t];
    __shared__ float r1[256], r2[256];
    float e[3]; float sum = 0.f, sq = 0.f;
#pragma unroll
    for (int j = 0; j < 3; ++j) {
        int i = tid + j * 256;
        float v = we[(size_t)id * HH + i] + pe[(size_t)s * HH + i] + te[i];
        e[j] = v; sum += v; sq += v * v;
    }
    r1[tid] = sum; r2[tid] = sq; __syncthreads();
    for (int o = 128; o > 0; o >>= 1) {
        if (tid < o) { r1[tid] += r1[tid + o]; r2[tid] += r2[tid + o]; }
        __syncthreads();
    }
    float mu = r1[0] * (1.0f / HH);
    float var = fmaxf(r2[0] * (1.0f / HH) - mu * mu, 0.f);
    float rs = rsqrtf(var + 1e-12f);
#pragma unroll
    for (int j = 0; j < 3; ++j) {
        int i = tid + j * 256;
        x[(size_t)t * HH + i] = f2bf((e[j] - mu) * rs * g[i] + beta[i]);
    }
}

// ---------------------------------------------------------------------------
// x = LN(x + y): wave-per-token, no barriers. WRITE_RELU=1 also writes
// relu(result) to xr (feeds head GEMM, eliminates a separate relu pass).
// ---------------------------------------------------------------------------
template<int WRITE_RELU>
__launch_bounds__(256)
__global__ void add_ln(unsigned short* __restrict__ x,
                       const unsigned short* __restrict__ y,
                       const float* __restrict__ g,
                       const float* __restrict__ beta,
                       unsigned short* __restrict__ xr) {
    const int t = blockIdx.x * 4 + (threadIdx.x >> 6);
    const int l = threadIdx.x & 63;
    const size_t base = (size_t)t * HH;
    float v[12];
    float sum = 0.f, sq = 0.f;
#pragma unroll
    for (int j = 0; j < 3; ++j) {
        uint2 xa = *(const uint2*)(x + base + j * 256 + l * 4);
        uint2 ya = *(const uint2*)(y + base + j * 256 + l * 4);
        const unsigned short* xp = (const unsigned short*)&xa;
        const unsigned short* yp = (const unsigned short*)&ya;
#pragma unroll
        for (int e = 0; e < 4; ++e) {
            float vv = bf2f(xp[e]) + bf2f(yp[e]);
            v[j * 4 + e] = vv;
            sum += vv; sq += vv * vv;
        }
    }
#pragma unroll
    for (int m = 1; m < 64; m <<= 1) {
        sum += __shfl_xor(sum, m);
        sq += __shfl_xor(sq, m);
    }
    float mu = sum * (1.0f / HH);
    float var = fmaxf(sq * (1.0f / HH) - mu * mu, 0.f);
    float rs = rsqrtf(var + 1e-12f);
#pragma unroll
    for (int j = 0; j < 3; ++j) {
        float4 gg = *(const float4*)(g + j * 256 + l * 4);
        float4 bb = *(const float4*)(beta + j * 256 + l * 4);
        float r0 = (v[j * 4 + 0] - mu) * rs * gg.x + bb.x;
        float r1 = (v[j * 4 + 1] - mu) * rs * gg.y + bb.y;
        float r2 = (v[j * 4 + 2] - mu) * rs * gg.z + bb.z;
        float r3 = (v[j * 4 + 3] - mu) * rs * gg.w + bb.w;
        uint2 st = {(unsigned)f2bf(r0) | ((unsigned)f2bf(r1) << 16),
                    (unsigned)f2bf(r2) | ((unsigned)f2bf(r3) << 16)};
        *(uint2*)(x + base + j * 256 + l * 4) = st;
        if (WRITE_RELU) {
            uint2 sr = {(unsigned)f2bf(fmaxf(r0, 0.f)) | ((unsigned)f2bf(fmaxf(r1, 0.f)) << 16),
                        (unsigned)f2bf(fmaxf(r2, 0.f)) | ((unsigned)f2bf(fmaxf(r3, 0.f)) << 16)};
            *(uint2*)(xr + base + j * 256 + l * 4) = sr;
        }
    }
}

__global__ void cumsum_k(const int* __restrict__ wpt, int* __restrict__ cum) {
    int b = blockIdx.x, w = threadIdx.x;
    int s = 0;
    for (int j = 0; j <= w; ++j) s += wpt[b * WW + j];
    cum[b * WW + w] = s;
}

__global__ void pool_softmax(const unsigned short* __restrict__ f2,
                             const int* __restrict__ cum,
                             float* __restrict__ out) {
    int t = blockIdx.x, b = t / SS, s = t % SS, tid = threadIdx.x;
    __shared__ float red[512];
    float val = -1e30f;
    bool act = tid < CC;
    if (act) {
        if (s < WW) {
            int end = cum[b * WW + s];
            int start = s ? cum[b * WW + s - 1] : 0;
            float su = 0.f;
            for (int j = start; j < end; ++j) su += bf2f(f2[((size_t)b * SS + j) * CC + tid]);
            val = su / (float)(end - start);
        } else {
            val = bf2f(f2[((size_t)b * SS + s) * CC + tid]);
        }
    }
    red[tid] = val; __syncthreads();
    for (int o = 256; o > 0; o >>= 1) {
        if (tid < o) red[tid] = fmaxf(red[tid], red[tid + o]);
        __syncthreads();
    }
    float mx = red[0]; __syncthreads();
    float e = act ? expf(val - mx) : 0.f;
    red[tid] = e; __syncthreads();
    for (int o = 256; o > 0; o >>= 1) {
        if (tid < o) red[tid] += red[tid + o];
        __syncthreads();
    }
    float inv = 1.0f / red[0];
    if (act) out[((size_t)b * SS + s) * CC + tid] = e * inv;
}

// ---------------------------------------------------------------------------
static inline size_t al256(size_t x) { return (x + 255) & ~(size_t)255; }

extern "C" void kernel_launch(void* const* d_in, const int* in_sizes, int n_in,
                              void* d_out, int out_size, void* d_ws, size_t ws_size,
                              hipStream_t stream) {
    const int* enc   = (const int*)d_in[0];
    const int* mask  = (const int*)d_in[1];
    const int* wpt   = (const int*)d_in[2];
    const float* word_emb = (const float*)d_in[3];
    const float* pos_emb  = (const float*)d_in[4];
    const float* type_emb = (const float*)d_in[5];
    const float* eln_s = (const float*)d_in[6];
    const float* eln_b = (const float*)d_in[7];
    const float* Wq = (const float*)d_in[8];
    const float* bq = (const float*)d_in[9];
    const float* Wk = (const float*)d_in[10];
    const float* bk = (const float*)d_in[11];
    const float* Wv = (const float*)d_in[12];
    const float* bv = (const float*)d_in[13];
    const float* Wo = (const float*)d_in[14];
    const float* bo = (const float*)d_in[15];
    const float* ln1s = (const float*)d_in[16];
    const float* ln1b = (const float*)d_in[17];
    const float* Wi = (const float*)d_in[18];
    const float* bi = (const float*)d_in[19];
    const float* Wo2 = (const float*)d_in[20];
    const float* bo2 = (const float*)d_in[21];
    const float* ln2s = (const float*)d_in[22];
    const float* ln2b = (const float*)d_in[23];
    const float* w1 = (const float*)d_in[24];
    const float* b1 = (const float*)d_in[25];
    const float* w2 = (const float*)d_in[26];
    const float* b2 = (const float*)d_in[27];

    unsigned char* ws = (unsigned char*)d_ws;
    size_t off = 0;
    unsigned short* x    = (unsigned short*)(ws + off); off = al256(off + (size_t)NTOK * HH * 2);
    unsigned short* qkv  = (unsigned short*)(ws + off); off = al256(off + (size_t)NTOK * QKVN * 2);
    unsigned short* ctx  = (unsigned short*)(ws + off); off = al256(off + (size_t)NTOK * HH * 2);
    unsigned short* proj = (unsigned short*)(ws + off); off = al256(off + (size_t)NTOK * HH * 2);
    unsigned short* ff   = (unsigned short*)(ws + off); off = al256(off + (size_t)NTOK * FFD * 2);
    unsigned short* f1   = (unsigned short*)(ws + off); off = al256(off + (size_t)NTOK * 1024 * 2);
    unsigned short* f2   = (unsigned short*)(ws + off); off = al256(off + (size_t)NTOK * CC * 2);
    unsigned short* xr   = (unsigned short*)(ws + off); off = al256(off + (size_t)NTOK * HH * 2);
    float* mb            = (float*)(ws + off);          off = al256(off + (size_t)NTOK * 4);
    int* cum             = (int*)(ws + off);            off = al256(off + (size_t)BB * WW * 4);
    float* bqkv          = (float*)(ws + off);          off = al256(off + (size_t)LL * QKVN * 4);
    size_t offFast = off;
    unsigned short* WqkvT = (unsigned short*)(ws + offFast); offFast = al256(offFast + (size_t)LL * QKVN * HH * 2);
    unsigned short* WoT   = (unsigned short*)(ws + offFast); offFast = al256(offFast + (size_t)LL * HH * HH * 2);
    unsigned short* WiT   = (unsigned short*)(ws + offFast); offFast = al256(offFast + (size_t)LL * FFD * HH * 2);
    unsigned short* Wo2T  = (unsigned short*)(ws + offFast); offFast = al256(offFast + (size_t)LL * HH * FFD * 2);
    unsigned short* w1T   = (unsigned short*)(ws + offFast); offFast = al256(offFast + (size_t)1024 * HH * 2);
    unsigned short* w2T   = (unsigned short*)(ws + offFast); offFast = al256(offFast + (size_t)512 * 1024 * 2);
    const bool fast = (ws_size >= offFast);

    build_maskbias<<<NTOK / 256, 256, 0, stream>>>(mask, mb);
    concat_bias<<<(LL * QKVN + 255) / 256, 256, 0, stream>>>(bq, bk, bv, bqkv);

    if (fast) {
        transpose_w<<<dim3(24, 24, LL), 256, 0, stream>>>(Wq, WqkvT, HH, HH, (long)HH * HH, (long)QKVN * HH);
        transpose_w<<<dim3(24, 24, LL), 256, 0, stream>>>(Wk, WqkvT + (size_t)HH * HH, HH, HH, (long)HH * HH, (long)QKVN * HH);
        transpose_w<<<dim3(24, 24, LL), 256, 0, stream>>>(Wv, WqkvT + (size_t)2 * HH * HH, HH, HH, (long)HH * HH, (long)QKVN * HH);
        transpose_w<<<dim3(24, 24, LL), 256, 0, stream>>>(Wo, WoT, HH, HH, (long)HH * HH, (long)HH * HH);
        transpose_w<<<dim3(96, 24, LL), 256, 0, stream>>>(Wi, WiT, HH, FFD, (long)HH * FFD, (long)FFD * HH);
        transpose_w<<<dim3(24, 96, LL), 256, 0, stream>>>(Wo2, Wo2T, FFD, HH, (long)FFD * HH, (long)HH * FFD);
        transpose_w<<<dim3(32, 24, 1), 256, 0, stream>>>(w1, w1T, HH, 1024, 0, 0);
        transpose_w<<<dim3(16, 32, 1), 256, 0, stream>>>(w2, w2T, 1024, CC, 0, 0);
    }

    embed_ln<<<NTOK, 256, 0, stream>>>(enc, word_emb, pos_emb, type_emb, eln_s, eln_b, x);

    const dim3 gQKV(QKVN / 128, NTOK / 128);    // 576 blocks, 128x128 (512 thr)
    const dim3 gWo(HH / 64, NTOK / 64);         // 768 blocks, 64x64 BK64 (512 thr)
    const dim3 gFF1(FFD / 128, NTOK / 128);     // 768 blocks, 128x128 (512 thr)
    const dim3 gFF2(HH / 64, NTOK / 64);        // 768 blocks, 64x64 BK64 (512 thr)
    const dim3 gH1(1024 / 64, NTOK / 64);       // 1024 blocks, 64x64 BK64 (512 thr)
    const dim3 gH2(7, NTOK / 64);               // 448 blocks, 64x64 BK64 (512 thr)
    const dim3 gAttn(4, NHH, BB);

    for (int l = 0; l < LL; ++l) {
        if (fast) {
            gemm128<0><<<gQKV, 512, 0, stream>>>(x, WqkvT + (size_t)l * QKVN * HH, bqkv + l * QKVN, qkv, NTOK, QKVN, HH, QKVN);
        } else {
            const dim3 g64(HH / 64, NTOK / 64);
            gemm_aw<0, 0><<<g64, 256, 0, stream>>>(x, Wq + (size_t)l * HH * HH, bq + l * HH, qkv, NTOK, HH, HH, QKVN);
            gemm_aw<0, 0><<<g64, 256, 0, stream>>>(x, Wk + (size_t)l * HH * HH, bk + l * HH, qkv + HH, NTOK, HH, HH, QKVN);
            gemm_aw<0, 0><<<g64, 256, 0, stream>>>(x, Wv + (size_t)l * HH * HH, bv + l * HH, qkv + 2 * HH, NTOK, HH, HH, QKVN);
        }
        attention_mfma<<<gAttn, 256, 0, stream>>>(qkv, mb, ctx);
        if (fast) {
            gemm64<0><<<gWo, 512, 0, stream>>>(ctx, WoT + (size_t)l * HH * HH, bo + l * HH, proj, NTOK, HH, HH, HH);
        } else {
            gemm_aw<0, 0><<<dim3(HH / 64, NTOK / 64), 256, 0, stream>>>(ctx, Wo + (size_t)l * HH * HH, bo + l * HH, proj, NTOK, HH, HH, HH);
        }
        add_ln<0><<<NTOK / 4, 256, 0, stream>>>(x, proj, ln1s + l * HH, ln1b + l * HH, nullptr);
        if (fast) {
            gemm128<1><<<gFF1, 512, 0, stream>>>(x, WiT + (size_t)l * FFD * HH, bi + l * FFD, ff, NTOK, FFD, HH, FFD);
            gemm64<0><<<gFF2, 512, 0, stream>>>(ff, Wo2T + (size_t)l * HH * FFD, bo2 + l * HH, proj, NTOK, HH, FFD, HH);
        } else {
            gemm_aw<0, 1><<<dim3(FFD / 64, NTOK / 64), 256, 0, stream>>>(x, Wi + (size_t)l * HH * FFD, bi + l * FFD, ff, NTOK, FFD, HH, FFD);
            gemm_aw<0, 0><<<dim3(HH / 64, NTOK / 64), 256, 0, stream>>>(ff, Wo2 + (size_t)l * FFD * HH, bo2 + l * HH, proj, NTOK, HH, FFD, HH);
        }
        if (l == LL - 1)
            add_ln<1><<<NTOK / 4, 256, 0, stream>>>(x, proj, ln2s + l * HH, ln2b + l * HH, xr);
        else
            add_ln<0><<<NTOK / 4, 256, 0, stream>>>(x, proj, ln2s + l * HH, ln2b + l * HH, nullptr);
    }

    // head: H1 fuses relu into epilogue (f1 = relu(xr@w1+b1)); H2 plain.
    if (fast) {
        gemm64<2><<<gH1, 512, 0, stream>>>(xr, w1T, b1, f1, NTOK, 1024, HH, 1024);
        gemm64<0><<<gH2, 512, 0, stream>>>(f1, w2T, b2, f2, NTOK, CC, 1024, CC);
    } else {
        gemm_aw<0, 2><<<dim3(1024 / 64, NTOK / 64), 256, 0, stream>>>(xr, w1, b1, f1, NTOK, 1024, HH, 1024);
        gemm_aw<0, 0><<<dim3(7, NTOK / 64), 256, 0, stream>>>(f1, w2, b2, f2, NTOK, CC, 1024, CC);
    }
    cumsum_k<<<BB, WW, 0, stream>>>(wpt, cum);
    pool_softmax<<<NTOK, 512, 0, stream>>>(f2, cum, (float*)d_out);
}